// Round 3
// baseline (28679.175 us; speedup 1.0000x reference)
//
#include <hip/hip_runtime.h>
#include <hip/hip_bf16.h>

#define T_STEPS 2048
#define HID 256
#define INF 72
#define OUTF 90

#define VT 46   // weight tiles per wave in VGPR/AGPR (46*4 = 184 regs)
#define LT 18   // weight tiles per wave in LDS (18KB/wave * 8 = 144KB)

typedef __attribute__((ext_vector_type(4))) float f32x4;
typedef __attribute__((ext_vector_type(8))) short s16x8;

__device__ __forceinline__ unsigned short f2bf(float f) {
  union { float f; unsigned u; } v; v.f = f;
  unsigned r = (v.u + 0x7FFFu + ((v.u >> 16) & 1u)) >> 16;   // RNE
  return (unsigned short)r;
}
__device__ __forceinline__ float bf2f(unsigned short s) {
  union { unsigned u; float f; } v; v.u = ((unsigned)s) << 16;
  return v.f;
}
__device__ __forceinline__ float sigm(float x) { return 1.f / (1.f + __expf(-x)); }
__device__ __forceinline__ float tanh_f(float x) { return 1.f - 2.f / (1.f + __expf(2.f * x)); }

// ---------------- input projection: h0 = relu(x @ W1^T + b1) ----------------
__global__ __launch_bounds__(256) void inproj(const float* __restrict__ x,
                                              const float* __restrict__ W1,
                                              const float* __restrict__ b1,
                                              float* __restrict__ h0) {
  __shared__ float w1s[HID][INF + 1];
  __shared__ float xs[16][INF];
  const int tid = threadIdx.x;
  const int r0 = blockIdx.x * 16;
  for (int i = tid; i < HID * INF; i += 256) w1s[i / INF][i % INF] = W1[i];
  for (int i = tid; i < 16 * INF; i += 256)
    xs[i / INF][i % INF] = x[(size_t)(r0 + i / INF) * INF + (i % INF)];
  __syncthreads();
  const float bj = b1[tid];
  for (int r = 0; r < 16; ++r) {
    float acc = bj;
#pragma unroll 8
    for (int k = 0; k < INF; ++k) acc += xs[r][k] * w1s[tid][k];
    h0[(size_t)(r0 + r) * HID + tid] = fmaxf(acc, 0.f);
  }
}

// ---------------- pack Wih (both layers) f32 -> bf16, same layout ----------------
__global__ __launch_bounds__(256) void wpack(const float* __restrict__ w,
                                             unsigned short* __restrict__ o) {
  const size_t i = ((size_t)blockIdx.x * 256 + threadIdx.x) * 8;
  f32x4 a = *(const f32x4*)(w + i);
  f32x4 b = *(const f32x4*)(w + i + 4);
  s16x8 v;
#pragma unroll
  for (int e = 0; e < 4; ++e) { v[e] = (short)f2bf(a[e]); v[4 + e] = (short)f2bf(b[e]); }
  *(s16x8*)(o + i) = v;
}

// ------------- gi GEMM (MFMA): one block per timestep t -------------
// gi[t][w8][q][lane][ug*4+r] = h0[t] @ Wih^T + bih + bhh  (bf16 fragment file)
// 4 waves; wave wg covers units [64wg, 64wg+64) as 4 unit-tiles (ug2).
__global__ __launch_bounds__(256) void gi_mfma(const float* __restrict__ h,
                                               const unsigned short* __restrict__ wb, // bf16 [1024][256]
                                               const float* __restrict__ bih,
                                               const float* __restrict__ bhh,
                                               unsigned short* __restrict__ gi) {
  __shared__ __align__(16) unsigned short hs[16 * 256];
  __shared__ float bs[1024];
  const int tid = threadIdx.x;
  const int t = blockIdx.x;
  const int lane = tid & 63;
  const int wg = tid >> 6;
  const int j = lane & 15;
  const int hi = lane >> 4;
  for (int i = tid; i < 1024; i += 256) bs[i] = bih[i] + bhh[i];
  {
    const int row = tid >> 4;
    const int c0 = (tid & 15) * 16;
    const float* src = h + ((size_t)t * 16 + row) * 256 + c0;
    f32x4 v0 = *(const f32x4*)(src);
    f32x4 v1 = *(const f32x4*)(src + 4);
    f32x4 v2 = *(const f32x4*)(src + 8);
    f32x4 v3 = *(const f32x4*)(src + 12);
    s16x8 p0, p1;
#pragma unroll
    for (int e = 0; e < 4; ++e) {
      p0[e] = (short)f2bf(v0[e]); p0[4 + e] = (short)f2bf(v1[e]);
      p1[e] = (short)f2bf(v2[e]); p1[4 + e] = (short)f2bf(v3[e]);
    }
    const int swz = (row & 7) << 4;
    *(s16x8*)((char*)hs + (((row << 9) + (c0 << 1)) ^ swz)) = p0;
    *(s16x8*)((char*)hs + (((row << 9) + ((c0 + 8) << 1)) ^ swz)) = p1;
  }
  __syncthreads();
  f32x4 acc[4][4] = {};   // [ug2][q]
#pragma unroll
  for (int kt = 0; kt < 8; ++kt) {
    const int k = kt * 32 + hi * 8;
    const int koff = ((j << 9) + (k << 1)) ^ ((j & 7) << 4);
    const s16x8 a = *(const s16x8*)((const char*)hs + koff);
#pragma unroll
    for (int ug2 = 0; ug2 < 4; ++ug2)
#pragma unroll
      for (int q = 0; q < 4; ++q) {
        const s16x8 b = *(const s16x8*)(wb + (((size_t)(q << 8) + wg * 64 + ug2 * 16 + j) << 8) + k);
        acc[ug2][q] = __builtin_amdgcn_mfma_f32_16x16x32_bf16(a, b, acc[ug2][q], 0, 0, 0);
      }
  }
#pragma unroll
  for (int m = 0; m < 2; ++m)
#pragma unroll
    for (int q = 0; q < 4; ++q) {
      const int u0 = wg * 64 + (2 * m) * 16 + j;
      const float b0 = bs[(q << 8) + u0];
      const float b1 = bs[(q << 8) + u0 + 16];
      s16x8 o;
#pragma unroll
      for (int r = 0; r < 4; ++r) {
        o[r]     = (short)f2bf(acc[2 * m][q][r] + b0);
        o[4 + r] = (short)f2bf(acc[2 * m + 1][q][r] + b1);
      }
      *(s16x8*)(gi + ((((size_t)t * 8 + wg * 2 + m) * 4 + q) << 9) + lane * 8) = o;
    }
}

// ---------------- single-WG LSTM scan, no vmcnt-drain barrier, 2-step gi prefetch ----------------
__global__ __launch_bounds__(512, 2) void lstm_scan(
    const unsigned short* __restrict__ gi,   // frag bf16 [T][8][4][64][8]
    const float* __restrict__ Whh,           // [1024][256]
    const int* __restrict__ lengths,
    float* __restrict__ hout)                // [T][16][256]
{
  extern __shared__ char smem[];
  char* hbase = smem + 147456;
  const int tid  = threadIdx.x;
  const int lane = tid & 63;
  const int w    = tid >> 6;
  const int j    = lane & 15;
  const int hi   = lane >> 4;

  s16x8 bfrV[VT];
#pragma unroll
  for (int ug = 0; ug < 2; ++ug)
#pragma unroll
    for (int kt = 0; kt < 8; ++kt)
#pragma unroll
      for (int q = 0; q < 4; ++q) {
        const int tau = (ug * 8 + kt) * 4 + q;
        const int u = w * 32 + ug * 16 + j;
        const float* src = Whh + (size_t)(q * 256 + u) * 256 + kt * 32 + hi * 8;
        s16x8 v;
#pragma unroll
        for (int e = 0; e < 8; ++e) v[e] = (short)f2bf(src[e]);
        if (tau < VT) bfrV[tau] = v;
        else *(s16x8*)(smem + (w * LT + (tau - VT)) * 1024 + lane * 16) = v;
      }
  for (int i = tid; i < 4096; i += 512) ((float*)hbase)[i] = 0.f;
  __syncthreads();

  int len[4];
#pragma unroll
  for (int r = 0; r < 4; ++r) len[r] = lengths[hi * 4 + r];
  float c[8] = {0.f, 0.f, 0.f, 0.f, 0.f, 0.f, 0.f, 0.f};
  unsigned short hprev[8] = {0, 0, 0, 0, 0, 0, 0, 0};

  const unsigned short* gptr = gi + ((size_t)w * 4 * 64 + lane) * 8;

  auto GATES = [&](int t, int ug, f32x4 (&acc)[4], char* hn) {
    const int u = w * 32 + ug * 16 + j;
#pragma unroll
    for (int r = 0; r < 4; ++r) {
      const int ci = ug * 4 + r;
      const float i_ = sigm(acc[0][r]);
      const float f_ = sigm(acc[1][r]);
      const float tg = tanh_f(acc[2][r]);
      const float o_ = sigm(acc[3][r]);
      const float cn = f_ * c[ci] + i_ * tg;
      const float hv = o_ * tanh_f(cn);
      const bool m = t < len[r];
      c[ci] = m ? cn : c[ci];
      const unsigned short hb = m ? f2bf(hv) : hprev[ci];
      hprev[ci] = hb;
      const int b = hi * 4 + r;
      const int hoff = ((b << 9) + (u << 1)) ^ ((b & 7) << 4);
      *(unsigned short*)(hn + hoff) = hb;
      hout[((size_t)t * 16 + b) * HID + u] = m ? hv : 0.f;
    }
  };

  auto STEP = [&](int t, s16x8 (&gfr)[4], int tpre) {
    const char* hc = hbase + (t & 1) * 8192;
    char* hn = hbase + ((t + 1) & 1) * 8192;
    f32x4 acc[4];
    float g1[4][4];
#pragma unroll
    for (int q = 0; q < 4; ++q)
#pragma unroll
      for (int r = 0; r < 4; ++r) {
        acc[q][r] = bf2f((unsigned short)gfr[q][r]);
        g1[q][r]  = bf2f((unsigned short)gfr[q][4 + r]);
      }
    {  // prefetch gi[t+2] into the just-freed registers (2-step distance)
      const unsigned short* gnx = gptr + (size_t)tpre * 16384;
#pragma unroll
      for (int q = 0; q < 4; ++q) gfr[q] = *(const s16x8*)(gnx + q * 512);
    }
    // ug = 0 (all weight tiles in registers)
#pragma unroll
    for (int kt = 0; kt < 8; ++kt) {
      const int k = kt * 32 + hi * 8;
      const int koff = ((j << 9) + (k << 1)) ^ ((j & 7) << 4);
      const s16x8 a = *(const s16x8*)(hc + koff);
#pragma unroll
      for (int q = 0; q < 4; ++q)
        acc[q] = __builtin_amdgcn_mfma_f32_16x16x32_bf16(a, bfrV[kt * 4 + q], acc[q], 0, 0, 0);
    }
    GATES(t, 0, acc, hn);
    // ug = 1 (tail tiles come from LDS)
#pragma unroll
    for (int q = 0; q < 4; ++q) {
      f32x4 tmp;
#pragma unroll
      for (int r = 0; r < 4; ++r) tmp[r] = g1[q][r];
      acc[q] = tmp;
    }
#pragma unroll
    for (int kt = 0; kt < 8; ++kt) {
      const int k = kt * 32 + hi * 8;
      const int koff = ((j << 9) + (k << 1)) ^ ((j & 7) << 4);
      const s16x8 a = *(const s16x8*)(hc + koff);
#pragma unroll
      for (int q = 0; q < 4; ++q) {
        const int tau = (8 + kt) * 4 + q;
        s16x8 bw;
        if (tau < VT) bw = bfrV[tau];
        else bw = *(const s16x8*)(smem + (w * LT + (tau - VT)) * 1024 + lane * 16);
        acc[q] = __builtin_amdgcn_mfma_f32_16x16x32_bf16(a, bw, acc[q], 0, 0, 0);
      }
    }
    GATES(t, 1, acc, hn);
    // LDS-only barrier: hout stores + gi prefetch stay in flight (no vmcnt drain)
    asm volatile("s_waitcnt lgkmcnt(0)" ::: "memory");
    __builtin_amdgcn_s_barrier();
    asm volatile("" ::: "memory");
  };

  s16x8 gfrE[4], gfrO[4];
#pragma unroll
  for (int q = 0; q < 4; ++q) {
    gfrE[q] = *(const s16x8*)(gptr + q * 512);
    gfrO[q] = *(const s16x8*)(gptr + 16384 + q * 512);
  }
  for (int t = 0; t < T_STEPS; t += 2) {
    STEP(t,     gfrE, (t + 2 < T_STEPS) ? t + 2 : T_STEPS - 1);
    STEP(t + 1, gfrO, (t + 3 < T_STEPS) ? t + 3 : T_STEPS - 1);
  }
}

// ---------------- output projection: y = mask ? h2 @ W2^T + b2 : 0 ----------------
__global__ __launch_bounds__(256) void outproj(const float* __restrict__ h2,
                                               const float* __restrict__ W2,
                                               const float* __restrict__ b2,
                                               const int* __restrict__ lengths,
                                               float* __restrict__ y) {
  __shared__ float w2s[OUTF][HID + 1];
  __shared__ float hs[8][HID + 1];
  const int tid = threadIdx.x;
  const int r0 = blockIdx.x * 8;
  for (int i = tid; i < OUTF * HID; i += 256) w2s[i / HID][i % HID] = W2[i];
  for (int i = tid; i < 8 * HID; i += 256)
    hs[i / HID][i % HID] = h2[(size_t)(r0 + i / HID) * HID + (i % HID)];
  __syncthreads();
  for (int oi = tid; oi < 8 * OUTF; oi += 256) {
    const int r = oi / OUTF, o = oi % OUTF;
    const int row = r0 + r, t = row >> 4, b = row & 15;
    float acc = b2[o];
#pragma unroll 8
    for (int k = 0; k < HID; ++k) acc += hs[r][k] * w2s[o][k];
    y[(size_t)row * OUTF + o] = (t < lengths[b]) ? acc : 0.f;
  }
}

extern "C" void kernel_launch(void* const* d_in, const int* in_sizes, int n_in,
                              void* d_out, int out_size, void* d_ws, size_t ws_size,
                              hipStream_t stream) {
  const float* x      = (const float*)d_in[0];
  const int*   lengths= (const int*)d_in[1];
  const float* W1     = (const float*)d_in[2];
  const float* b1     = (const float*)d_in[3];
  const float* Wih    = (const float*)d_in[4];   // [2][1024][256]
  const float* Whh    = (const float*)d_in[5];   // [2][1024][256]
  const float* bih    = (const float*)d_in[6];   // [2][1024]
  const float* bhh    = (const float*)d_in[7];
  const float* W2     = (const float*)d_in[8];
  const float* b2     = (const float*)d_in[9];
  float* out = (float*)d_out;

  char* ws = (char*)d_ws;
  float*          h0 = (float*)(ws);                          // 33,554,432 B
  unsigned short* gf = (unsigned short*)(ws + 33554432);      // 67,108,864 B
  float*          h1 = (float*)(ws + 100663296);              // 33,554,432 B
  float*          h2 = (float*)(ws + 134217728);              // 33,554,432 B
  unsigned short* wb = (unsigned short*)(ws + 167772160);     //  1,048,576 B (bf16 Wih, both layers)

  hipFuncSetAttribute((const void*)lstm_scan,
                      hipFuncAttributeMaxDynamicSharedMemorySize, 163840);

  wpack<<<256, 256, 0, stream>>>(Wih, wb);
  inproj<<<2048, 256, 0, stream>>>(x, W1, b1, h0);

  gi_mfma<<<2048, 256, 0, stream>>>(h0, wb, bih, bhh, gf);
  lstm_scan<<<1, 512, 163840, stream>>>(gf, Whh, lengths, h1);

  gi_mfma<<<2048, 256, 0, stream>>>(h1, wb + 262144, bih + 1024, bhh + 1024, gf);
  lstm_scan<<<1, 512, 163840, stream>>>(gf, Whh + 262144, lengths, h2);

  outproj<<<4096, 256, 0, stream>>>(h2, W2, b2, lengths, out);
}

// Round 4
// 11259.302 us; speedup vs baseline: 2.5472x; 2.5472x over previous
//
#include <hip/hip_runtime.h>
#include <hip/hip_bf16.h>

#define T_STEPS 2048
#define HID 256
#define INF 72
#define OUTF 90

#define VT 32     // ug0 weight tiles per wave in regs (32*4 = 128 VGPRs)
#define LT 17     // ug1 weight tiles per wave in LDS (17KB * 8 waves = 136KB)
#define HSTR 528  // LDS h row stride in bytes (16B-aligned, kills mod-128 aliasing)

typedef __attribute__((ext_vector_type(4))) float f32x4;
typedef __attribute__((ext_vector_type(8))) short s16x8;
typedef __attribute__((ext_vector_type(4))) short s16x4;

__device__ __forceinline__ unsigned short f2bf(float f) {
  union { float f; unsigned u; } v; v.f = f;
  unsigned r = (v.u + 0x7FFFu + ((v.u >> 16) & 1u)) >> 16;   // RNE
  return (unsigned short)r;
}
__device__ __forceinline__ float bf2f(unsigned short s) {
  union { unsigned u; float f; } v; v.u = ((unsigned)s) << 16;
  return v.f;
}
__device__ __forceinline__ float sigm(float x) { return 1.f / (1.f + __expf(-x)); }
__device__ __forceinline__ float tanh_f(float x) { return 1.f - 2.f / (1.f + __expf(2.f * x)); }

// ---------------- input projection: h0 = relu(x @ W1^T + b1) ----------------
__global__ __launch_bounds__(256) void inproj(const float* __restrict__ x,
                                              const float* __restrict__ W1,
                                              const float* __restrict__ b1,
                                              float* __restrict__ h0) {
  __shared__ float w1s[HID][INF + 1];
  __shared__ float xs[16][INF];
  const int tid = threadIdx.x;
  const int r0 = blockIdx.x * 16;
  for (int i = tid; i < HID * INF; i += 256) w1s[i / INF][i % INF] = W1[i];
  for (int i = tid; i < 16 * INF; i += 256)
    xs[i / INF][i % INF] = x[(size_t)(r0 + i / INF) * INF + (i % INF)];
  __syncthreads();
  const float bj = b1[tid];
  for (int r = 0; r < 16; ++r) {
    float acc = bj;
#pragma unroll 8
    for (int k = 0; k < INF; ++k) acc += xs[r][k] * w1s[tid][k];
    h0[(size_t)(r0 + r) * HID + tid] = fmaxf(acc, 0.f);
  }
}

// ---------------- pack f32 -> bf16 (524288 elements per call) ----------------
__global__ __launch_bounds__(256) void wpack(const float* __restrict__ w,
                                             unsigned short* __restrict__ o) {
  const size_t i = ((size_t)blockIdx.x * 256 + threadIdx.x) * 8;
  f32x4 a = *(const f32x4*)(w + i);
  f32x4 b = *(const f32x4*)(w + i + 4);
  s16x8 v;
#pragma unroll
  for (int e = 0; e < 4; ++e) { v[e] = (short)f2bf(a[e]); v[4 + e] = (short)f2bf(b[e]); }
  *(s16x8*)(o + i) = v;
}

// ------------- layer-1 gi GEMM (MFMA): one block per timestep t -------------
// gf1[t][w8][q][lane][ug*4+r] = h0[t] @ Wih1^T + bih1 + bhh1 (bf16 fragments)
__global__ __launch_bounds__(256) void gi_mfma(const float* __restrict__ h,
                                               const unsigned short* __restrict__ wb,
                                               const float* __restrict__ bih,
                                               const float* __restrict__ bhh,
                                               unsigned short* __restrict__ gi) {
  __shared__ __align__(16) char hs[16 * HSTR];
  __shared__ float bs[1024];
  const int tid = threadIdx.x;
  const int t = blockIdx.x;
  const int lane = tid & 63;
  const int wg = tid >> 6;
  const int j = lane & 15;
  const int hi = lane >> 4;
  for (int i = tid; i < 1024; i += 256) bs[i] = bih[i] + bhh[i];
  {
    const int row = tid >> 4;
    const int c0 = (tid & 15) * 16;
    const float* src = h + ((size_t)t * 16 + row) * 256 + c0;
    f32x4 v0 = *(const f32x4*)(src);
    f32x4 v1 = *(const f32x4*)(src + 4);
    f32x4 v2 = *(const f32x4*)(src + 8);
    f32x4 v3 = *(const f32x4*)(src + 12);
    s16x8 p0, p1;
#pragma unroll
    for (int e = 0; e < 4; ++e) {
      p0[e] = (short)f2bf(v0[e]); p0[4 + e] = (short)f2bf(v1[e]);
      p1[e] = (short)f2bf(v2[e]); p1[4 + e] = (short)f2bf(v3[e]);
    }
    *(s16x8*)(hs + row * HSTR + c0 * 2) = p0;
    *(s16x8*)(hs + row * HSTR + c0 * 2 + 16) = p1;
  }
  __syncthreads();
  const int hread = j * HSTR + hi * 16;
  f32x4 acc[4][4] = {};   // [ug2][q]
#pragma unroll
  for (int kt = 0; kt < 8; ++kt) {
    const int k = kt * 32 + hi * 8;
    const s16x8 a = *(const s16x8*)(hs + hread + kt * 64);
#pragma unroll
    for (int ug2 = 0; ug2 < 4; ++ug2)
#pragma unroll
      for (int q = 0; q < 4; ++q) {
        const s16x8 b = *(const s16x8*)(wb + (((size_t)(q << 8) + wg * 64 + ug2 * 16 + j) << 8) + k);
        acc[ug2][q] = __builtin_amdgcn_mfma_f32_16x16x32_bf16(a, b, acc[ug2][q], 0, 0, 0);
      }
  }
#pragma unroll
  for (int m = 0; m < 2; ++m)
#pragma unroll
    for (int q = 0; q < 4; ++q) {
      const int u0 = wg * 64 + (2 * m) * 16 + j;
      const float b0 = bs[(q << 8) + u0];
      const float b1 = bs[(q << 8) + u0 + 16];
      s16x8 o;
#pragma unroll
      for (int r = 0; r < 4; ++r) {
        o[r]     = (short)f2bf(acc[2 * m][q][r] + b0);
        o[4 + r] = (short)f2bf(acc[2 * m + 1][q][r] + b1);
      }
      *(s16x8*)(gi + ((((size_t)t * 8 + wg * 2 + m) * 4 + q) << 9) + lane * 8) = o;
    }
}

// ================= fused pipeline: scan1 | gi2a | gi2b | scan2 =================

// ---- LSTM scan body (one block, all of Whh on one CU: regs + LDS + L2) ----
template <int ROLE>   // 0: layer1 (writes hb1 bf16, releases cnt_rel); 1: layer2 (writes hout f32, waits cntA/cntB)
__device__ __forceinline__ void scan_body(
    const unsigned short* __restrict__ gi,    // gi fragment file [T][8][4][64][8]
    const unsigned short* __restrict__ whbL,  // Whh bf16 [1024][256] (this layer)
    const int* __restrict__ lengths,
    unsigned short* __restrict__ hb1,
    float* __restrict__ hout,
    unsigned int* cnt_rel, unsigned int* cntA, unsigned int* cntB,
    char* smem)
{
  const int tid = threadIdx.x;
  const int lane = tid & 63;
  const int w = tid >> 6;
  const int j = lane & 15;
  const int hi = lane >> 4;
  char* wlds = smem;                     // 8 * 17 KB
  char* hbase = smem + 8 * LT * 1024;    // 2 * 8448

  // preload: tau<32 -> regs (all ug0); 32..48 -> LDS; 49..63 -> streamed from L2 per step
  s16x8 bfrV[VT];
#pragma unroll
  for (int ug = 0; ug < 2; ++ug)
#pragma unroll
    for (int kt = 0; kt < 8; ++kt)
#pragma unroll
      for (int q = 0; q < 4; ++q) {
        const int tau = (ug * 8 + kt) * 4 + q;
        if (tau >= VT + LT) continue;
        const int u = w * 32 + ug * 16 + j;
        const s16x8 v = *(const s16x8*)(whbL + ((size_t)(q * 256 + u) << 8) + kt * 32 + hi * 8);
        if (tau < VT) bfrV[tau] = v;
        else *(s16x8*)(wlds + (w * LT + (tau - VT)) * 1024 + lane * 16) = v;
      }
  for (int i = tid; i < 2 * 8448 / 4; i += 512) ((float*)hbase)[i] = 0.f;
  __syncthreads();

  int len[4];
#pragma unroll
  for (int r = 0; r < 4; ++r) len[r] = lengths[hi * 4 + r];
  float c[8] = {};
  unsigned short hprev[8] = {};

  const unsigned short* gwp = whbL + (size_t)(w * 32 + 16 + j) * 256 + hi * 8;  // ug1 weight rows
  const int hread = j * HSTR + hi * 16;
  unsigned cred = 0;

  // global-streamed ug1 tiles: linear i -> (kt,q) = (4,1)(4,2)(4,3)(5,0)(5,1)|(5,2)(5,3)(6,0)(6,1)(6,2)|(6,3)(7,0)(7,1)(7,2)(7,3)
#define GKT(i) (4 + ((i) + 1) / 4)
#define GQ(i)  (((i) + 1) & 3)

  for (int tg = 0; tg < T_STEPS; tg += 4) {
    if (ROLE == 1) {
      while (cred < (unsigned)(tg + 4)) {
        unsigned a = __hip_atomic_load(cntA, __ATOMIC_ACQUIRE, __HIP_MEMORY_SCOPE_AGENT);
        unsigned b = __hip_atomic_load(cntB, __ATOMIC_ACQUIRE, __HIP_MEMORY_SCOPE_AGENT);
        cred = a < b ? a : b;
        if (cred < (unsigned)(tg + 4)) __builtin_amdgcn_s_sleep(2);
      }
    }
    for (int ts = 0; ts < 4; ++ts) {
      const int t = tg + ts;
      const char* hc = hbase + (t & 1) * 8448;
      char* hn = hbase + ((t + 1) & 1) * 8448;
      const unsigned short* gb = gi + (((size_t)t * 8 + w) * 4) * 512 + lane * 8;

      // issue: gi ug0 halves + weight batch 1
      s16x4 gv0[4], gv1[4];
#pragma unroll
      for (int q = 0; q < 4; ++q) gv0[q] = *(const s16x4*)(gb + q * 512);
      s16x8 gw[15];
#pragma unroll
      for (int i = 0; i < 5; ++i) gw[i] = *(const s16x8*)(gwp + GQ(i) * 65536 + GKT(i) * 32);

      // ---- ug0: all weights in regs ----
      f32x4 acc[4] = {};
#pragma unroll
      for (int kt = 0; kt < 8; ++kt) {
        const s16x8 a = *(const s16x8*)(hc + hread + kt * 64);
#pragma unroll
        for (int q = 0; q < 4; ++q)
          acc[q] = __builtin_amdgcn_mfma_f32_16x16x32_bf16(a, bfrV[kt * 4 + q], acc[q], 0, 0, 0);
      }
      {  // gates ug0
        const int u = w * 32 + j;
#pragma unroll
        for (int r = 0; r < 4; ++r) {
          const float g0 = acc[0][r] + bf2f((unsigned short)gv0[0][r]);
          const float g1 = acc[1][r] + bf2f((unsigned short)gv0[1][r]);
          const float g2 = acc[2][r] + bf2f((unsigned short)gv0[2][r]);
          const float g3 = acc[3][r] + bf2f((unsigned short)gv0[3][r]);
          const float i_ = sigm(g0), f_ = sigm(g1), tg_ = tanh_f(g2), o_ = sigm(g3);
          const float cn = f_ * c[r] + i_ * tg_;
          const float hv = o_ * tanh_f(cn);
          const bool m = t < len[r];
          c[r] = m ? cn : c[r];
          const unsigned short hb = m ? f2bf(hv) : hprev[r];
          hprev[r] = hb;
          const int b = hi * 4 + r;
          *(unsigned short*)(hn + b * HSTR + u * 2) = hb;
          if (ROLE == 0) hb1[(size_t)t * 4096 + b * 256 + u] = m ? hb : (unsigned short)0;
          else           hout[((size_t)t * 16 + b) * 256 + u] = m ? hv : 0.f;
        }
      }
      // issue: gi ug1 halves + weight batch 2
#pragma unroll
      for (int q = 0; q < 4; ++q) gv1[q] = *(const s16x4*)(gb + q * 512 + 4);
#pragma unroll
      for (int i = 5; i < 10; ++i) gw[i] = *(const s16x8*)(gwp + GQ(i) * 65536 + GKT(i) * 32);

      // ---- ug1: weights from regs(kt0) + LDS + L2 stream ----
#pragma unroll
      for (int q = 0; q < 4; ++q) { f32x4 z = {}; acc[q] = z; }
#pragma unroll
      for (int kt = 0; kt < 8; ++kt) {
        const s16x8 a = *(const s16x8*)(hc + hread + kt * 64);
#pragma unroll
        for (int q = 0; q < 4; ++q) {
          const int tau = (8 + kt) * 4 + q;
          s16x8 bw;
          if (tau < VT) bw = bfrV[tau];
          else if (tau < VT + LT) bw = *(const s16x8*)(wlds + (w * LT + (tau - VT)) * 1024 + lane * 16);
          else bw = gw[(kt - 4) * 4 + q - 1];
          acc[q] = __builtin_amdgcn_mfma_f32_16x16x32_bf16(a, bw, acc[q], 0, 0, 0);
        }
        if (kt == 1) {
#pragma unroll
          for (int i = 10; i < 15; ++i) gw[i] = *(const s16x8*)(gwp + GQ(i) * 65536 + GKT(i) * 32);
        }
      }
      {  // gates ug1
        const int u = w * 32 + 16 + j;
#pragma unroll
        for (int r = 0; r < 4; ++r) {
          const int ci = 4 + r;
          const float g0 = acc[0][r] + bf2f((unsigned short)gv1[0][r]);
          const float g1 = acc[1][r] + bf2f((unsigned short)gv1[1][r]);
          const float g2 = acc[2][r] + bf2f((unsigned short)gv1[2][r]);
          const float g3 = acc[3][r] + bf2f((unsigned short)gv1[3][r]);
          const float i_ = sigm(g0), f_ = sigm(g1), tg_ = tanh_f(g2), o_ = sigm(g3);
          const float cn = f_ * c[ci] + i_ * tg_;
          const float hv = o_ * tanh_f(cn);
          const bool m = t < len[r];
          c[ci] = m ? cn : c[ci];
          const unsigned short hb = m ? f2bf(hv) : hprev[ci];
          hprev[ci] = hb;
          const int b = hi * 4 + r;
          *(unsigned short*)(hn + b * HSTR + u * 2) = hb;
          if (ROLE == 0) hb1[(size_t)t * 4096 + b * 256 + u] = m ? hb : (unsigned short)0;
          else           hout[((size_t)t * 16 + b) * 256 + u] = m ? hv : 0.f;
        }
      }
      if (ts == 3) {
        asm volatile("s_waitcnt vmcnt(0) lgkmcnt(0)" ::: "memory");
        __builtin_amdgcn_s_barrier();
        if (ROLE == 0 && tid == 0)
          __hip_atomic_store(cnt_rel, (unsigned)(t + 1), __ATOMIC_RELEASE, __HIP_MEMORY_SCOPE_AGENT);
      } else {
        asm volatile("s_waitcnt lgkmcnt(0)" ::: "memory");
        __builtin_amdgcn_s_barrier();
      }
      asm volatile("" ::: "memory");
    }
  }
#undef GKT
#undef GQ
}

// ---- gi2 producer: half the gates (qbase..qbase+1), Wih2 slice fully in regs ----
__device__ __forceinline__ void gi2_body(int qbase,
    const unsigned short* __restrict__ hb1,
    const unsigned short* __restrict__ wb2,
    const float* __restrict__ bih2, const float* __restrict__ bhh2,
    unsigned short* __restrict__ gf2,
    unsigned int* cnt_src, unsigned int* cnt_out)
{
  const int tid = threadIdx.x;
  const int lane = tid & 63;
  const int w = tid >> 6;
  const int j = lane & 15;
  const int hi = lane >> 4;

  s16x8 wfr[2][2][8];
  float bsum[2][2];
#pragma unroll
  for (int qh = 0; qh < 2; ++qh)
#pragma unroll
    for (int ug = 0; ug < 2; ++ug) {
      const int col = (qbase + qh) * 256 + w * 32 + ug * 16 + j;
      bsum[qh][ug] = bih2[col] + bhh2[col];
#pragma unroll
      for (int kt = 0; kt < 8; ++kt)
        wfr[qh][ug][kt] = *(const s16x8*)(wb2 + ((size_t)col << 8) + kt * 32 + hi * 8);
    }

  unsigned cred = 0;
  for (int tg = 0; tg < T_STEPS; tg += 4) {
    while (cred < (unsigned)(tg + 4)) {
      cred = __hip_atomic_load(cnt_src, __ATOMIC_ACQUIRE, __HIP_MEMORY_SCOPE_AGENT);
      if (cred < (unsigned)(tg + 4)) __builtin_amdgcn_s_sleep(2);
    }
    for (int ts = 0; ts < 4; ++ts) {
      const int t = tg + ts;
      const unsigned short* ab = hb1 + (size_t)t * 4096 + j * 256 + hi * 8;
      f32x4 acc[2][2] = {};
#pragma unroll
      for (int kt = 0; kt < 8; ++kt) {
        const s16x8 a = *(const s16x8*)(ab + kt * 32);
#pragma unroll
        for (int qh = 0; qh < 2; ++qh)
#pragma unroll
          for (int ug = 0; ug < 2; ++ug)
            acc[qh][ug] = __builtin_amdgcn_mfma_f32_16x16x32_bf16(a, wfr[qh][ug][kt], acc[qh][ug], 0, 0, 0);
      }
#pragma unroll
      for (int qh = 0; qh < 2; ++qh) {
        s16x8 o;
#pragma unroll
        for (int r = 0; r < 4; ++r) {
          o[r]     = (short)f2bf(acc[qh][0][r] + bsum[qh][0]);
          o[4 + r] = (short)f2bf(acc[qh][1][r] + bsum[qh][1]);
        }
        *(s16x8*)(gf2 + ((((size_t)t * 8 + w) * 4 + qbase + qh) << 9) + lane * 8) = o;
      }
    }
    asm volatile("s_waitcnt vmcnt(0)" ::: "memory");
    __builtin_amdgcn_s_barrier();
    if (tid == 0)
      __hip_atomic_store(cnt_out, (unsigned)(tg + 4), __ATOMIC_RELEASE, __HIP_MEMORY_SCOPE_AGENT);
    asm volatile("" ::: "memory");
  }
}

__global__ __launch_bounds__(512, 2) void fused_pipe(
    const unsigned short* __restrict__ gf1,
    const unsigned short* __restrict__ whb,   // Whh bf16 [2][1024][256]
    const unsigned short* __restrict__ wb,    // Wih bf16 [2][1024][256]
    const float* __restrict__ bih, const float* __restrict__ bhh,
    const int* __restrict__ lengths,
    unsigned short* hb1, unsigned short* gf2, float* hout2,
    unsigned int* cnts)
{
  extern __shared__ char smem[];
  const int bid = blockIdx.x;
  if (bid == 0)
    scan_body<0>(gf1, whb, lengths, hb1, nullptr, cnts, nullptr, nullptr, smem);
  else if (bid == 1)
    gi2_body(0, hb1, wb + 262144, bih + 1024, bhh + 1024, gf2, cnts, cnts + 16);
  else if (bid == 2)
    gi2_body(2, hb1, wb + 262144, bih + 1024, bhh + 1024, gf2, cnts, cnts + 32);
  else
    scan_body<1>(gf2, whb + 262144, lengths, nullptr, hout2, nullptr, cnts + 16, cnts + 32, smem);
}

// ---------------- output projection: y = mask ? h2 @ W2^T + b2 : 0 ----------------
__global__ __launch_bounds__(256) void outproj(const float* __restrict__ h2,
                                               const float* __restrict__ W2,
                                               const float* __restrict__ b2,
                                               const int* __restrict__ lengths,
                                               float* __restrict__ y) {
  __shared__ float w2s[OUTF][HID + 1];
  __shared__ float hs[8][HID + 1];
  const int tid = threadIdx.x;
  const int r0 = blockIdx.x * 8;
  for (int i = tid; i < OUTF * HID; i += 256) w2s[i / HID][i % HID] = W2[i];
  for (int i = tid; i < 8 * HID; i += 256)
    hs[i / HID][i % HID] = h2[(size_t)(r0 + i / HID) * HID + (i % HID)];
  __syncthreads();
  for (int oi = tid; oi < 8 * OUTF; oi += 256) {
    const int r = oi / OUTF, o = oi % OUTF;
    const int row = r0 + r, t = row >> 4, b = row & 15;
    float acc = b2[o];
#pragma unroll 8
    for (int k = 0; k < HID; ++k) acc += hs[r][k] * w2s[o][k];
    y[(size_t)row * OUTF + o] = (t < lengths[b]) ? acc : 0.f;
  }
}

extern "C" void kernel_launch(void* const* d_in, const int* in_sizes, int n_in,
                              void* d_out, int out_size, void* d_ws, size_t ws_size,
                              hipStream_t stream) {
  const float* x      = (const float*)d_in[0];
  const int*   lengths= (const int*)d_in[1];
  const float* W1     = (const float*)d_in[2];
  const float* b1     = (const float*)d_in[3];
  const float* Wih    = (const float*)d_in[4];
  const float* Whh    = (const float*)d_in[5];
  const float* bih    = (const float*)d_in[6];
  const float* bhh    = (const float*)d_in[7];
  const float* W2     = (const float*)d_in[8];
  const float* b2     = (const float*)d_in[9];
  float* out = (float*)d_out;

  char* ws = (char*)d_ws;
  float*          h0   = (float*)(ws);                          // 32 MB
  unsigned short* gf1  = (unsigned short*)(ws + 33554432);      // 64 MB
  unsigned short* hb1  = (unsigned short*)(ws + 100663296);     // 16 MB
  unsigned short* gf2  = (unsigned short*)(ws + 117440512);     // 64 MB
  float*          h2o  = (float*)(ws + 184549376);              // 32 MB
  unsigned short* wb   = (unsigned short*)(ws + 218103808);     // 1 MB (Wih bf16)
  unsigned short* whb  = (unsigned short*)(ws + 219152384);     // 1 MB (Whh bf16)
  unsigned int*   cnts = (unsigned int*)(ws + 220200960);       // 256 B

  hipFuncSetAttribute((const void*)fused_pipe,
                      hipFuncAttributeMaxDynamicSharedMemorySize, 156160);

  wpack<<<256, 256, 0, stream>>>(Wih, wb);
  wpack<<<256, 256, 0, stream>>>(Whh, whb);
  inproj<<<2048, 256, 0, stream>>>(x, W1, b1, h0);
  gi_mfma<<<2048, 256, 0, stream>>>(h0, wb, bih, bhh, gf1);

  hipMemsetAsync((void*)cnts, 0, 256, stream);
  fused_pipe<<<4, 512, 156160, stream>>>(gf1, whb, wb, bih, bhh, lengths,
                                         hb1, gf2, h2o, cnts);

  outproj<<<4096, 256, 0, stream>>>(h2o, W2, b2, lengths, out);
}